// Round 5
// baseline (1028.708 us; speedup 1.0000x reference)
//
#include <hip/hip_runtime.h>
#include <math.h>

#define DEV __device__ __forceinline__

typedef __attribute__((ext_vector_type(8))) unsigned short u16x8;
typedef __attribute__((ext_vector_type(8))) __bf16 bf16x8;
typedef __attribute__((ext_vector_type(4))) float f32x4;

static constexpr int TOK = 50176;   // 1024 windows * 49 tokens = B*H*W
static constexpr int DIMC = 384;
static constexpr float QSCALE = 0.17677669529663687f;  // 32^-0.5

DEV unsigned short f2bf(float f) {   // round-to-nearest-even fp32 -> bf16 bits
  union { float f; unsigned u; } v; v.f = f;
  unsigned r = v.u + 0x7fffu + ((v.u >> 16) & 1u);
  return (unsigned short)(r >> 16);
}

DEV f32x4 mfma16(bf16x8 a, bf16x8 b, f32x4 c) {
  return __builtin_amdgcn_mfma_f32_16x16x32_bf16(a, b, c, 0, 0, 0);
}

DEV void gload_lds16(const void* g, void* lds) {
  __builtin_amdgcn_global_load_lds(
      (const __attribute__((address_space(1))) void*)g,
      (__attribute__((address_space(3))) void*)lds, 16, 0, 0);
}

// fp32 weight -> bf16 bits
__global__ __launch_bounds__(256) void w2bf_kern(const float* __restrict__ in,
                                                 unsigned short* __restrict__ out, int n) {
  int i = blockIdx.x * 256 + threadIdx.x;
  if (i < n) out[i] = f2bf(in[i]);
}

// LayerNorm; WINDOW=true also applies roll(-3,-3)+window partition (gather form).
template<bool WINDOW>
__global__ __launch_bounds__(256) void ln_kern(const float* __restrict__ in,
                                               const float* __restrict__ gw,
                                               const float* __restrict__ gb,
                                               unsigned short* __restrict__ out) {
  const int row = blockIdx.x * 4 + (threadIdx.x >> 6);  // output row
  const int l = threadIdx.x & 63;
  int src = row;
  if (WINDOW) {
    const int wq = row / 49, nn = row - wq * 49;
    const int bb = wq >> 8, wi = wq & 255;
    int hh = (wi >> 4) * 7 + nn / 7 + 3;        if (hh >= 112) hh -= 112;
    int cc = (wi & 15) * 7 + (nn - (nn / 7) * 7) + 3; if (cc >= 112) cc -= 112;
    src = bb * 12544 + hh * 112 + cc;
  }
  const float* x = in + (size_t)src * DIMC;
  float v[6]; float s = 0.f, s2 = 0.f;
#pragma unroll
  for (int j = 0; j < 6; ++j) { float t = x[l + 64 * j]; v[j] = t; s += t; s2 += t * t; }
#pragma unroll
  for (int d = 1; d < 64; d <<= 1) { s += __shfl_xor(s, d); s2 += __shfl_xor(s2, d); }
  const float mean = s * (1.f / 384.f);
  const float var = s2 * (1.f / 384.f) - mean * mean;
  const float rs = rsqrtf(var + 1e-5f);
#pragma unroll
  for (int j = 0; j < 6; ++j) {
    int c = l + 64 * j;
    out[(size_t)row * DIMC + c] = f2bf((v[j] - mean) * rs * gw[c] + gb[c]);
  }
}

enum { E_BF16 = 0, E_BF16_SCALE = 1, E_SCATTER = 2, E_GELU = 3, E_RESOUT = 4 };

// C = A(MxK) @ W(NxK)^T + bias. 256x128 tile, BK=32, 8 waves (4m x 2n).
// 3-buffer LDS rotation, ONE barrier per K-step, counted vmcnt(3) (2-tile
// prefetch, 3 loads/thread/tile). XOR swizzle: pre-swizzled global source col
// + swizzled ds_read (rule #21); LDS dest linear for global_load_lds.
// Persistent grid of 512 blocks (2/CU resident), XCD-chunked col-fast tiles.
template<int EPI>
__global__ __launch_bounds__(512, 4) void gemm_bt(
    const unsigned short* __restrict__ A, const unsigned short* __restrict__ W,
    const float* __restrict__ bias, int K, int N, int nbx, int ntiles,
    unsigned short* __restrict__ outb,
    float* __restrict__ outf1, float* __restrict__ outf2,
    const float* __restrict__ res1, const float* __restrict__ res2) {
  __shared__ __align__(16) unsigned short sA[3][256 * 32];
  __shared__ __align__(16) unsigned short sB[3][128 * 32];
  const int t = threadIdx.x;
  const int wv = t >> 6, l = t & 63;
  const int wm = (wv >> 1) * 64, wn = (wv & 1) * 64;

  // persistent mapping: grid == 512; XCD x owns tiles [x*64 + k*512 ...]
  const int wgid0 = (blockIdx.x & 7) * 64 + (blockIdx.x >> 3);

  // staging: thread t -> row (t>>2) in a 128-row round, slot (t&3); src col pre-swizzled
  const int srow = t >> 2;                                  // 0..127
  const int scol = ((t & 3) ^ ((srow >> 1) & 3)) * 8;       // elements (invariant for row+128)
  const int ldsW = wv * 512;  // per-wave 1KB (elements) within a 4K-element round

  const int g = l >> 4, lr = l & 15;
  const int swz = ((lr >> 1) & 3) << 4;  // read-side XOR (bytes)
  const f32x4 fzero = {0.f, 0.f, 0.f, 0.f};
  const int ntt = K >> 5;

  for (int T = wgid0; T < ntiles; T += 512) {
    const int n0 = (T % nbx) * 128, m0 = (T / nbx) * 256;

    f32x4 acc[4][4];
#pragma unroll
    for (int i = 0; i < 4; ++i)
#pragma unroll
      for (int j = 0; j < 4; ++j) acc[i][j] = fzero;

    const unsigned short* pA = A + (size_t)(m0 + srow) * K + scol;
    const unsigned short* pB = W + (size_t)(n0 + srow) * K + scol;

    // prologue: stage K-tiles 0,1 into bufs 0,1
#pragma unroll
    for (int p = 0; p < 2; ++p) {
      gload_lds16(pA + p * 32, &sA[p][ldsW]);
      gload_lds16(pA + (size_t)128 * K + p * 32, &sA[p][4096 + ldsW]);
      gload_lds16(pB + p * 32, &sB[p][ldsW]);
    }
    for (int tt = 0; tt < ntt; ++tt) {
      if (tt + 1 < ntt) {
        asm volatile("s_waitcnt vmcnt(3)" ::: "memory");  // tile tt landed; tt+1 in flight
      } else {
        asm volatile("s_waitcnt vmcnt(0)" ::: "memory");
      }
      __builtin_amdgcn_s_barrier();
      asm volatile("" ::: "memory");
      if (tt + 2 < ntt) {  // stage tile tt+2 into buf (tt+2)%3 (last read at iter tt-1)
        const int kt = (tt + 2) << 5;
        const int b2 = (tt + 2) % 3;
        gload_lds16(pA + kt, &sA[b2][ldsW]);
        gload_lds16(pA + (size_t)128 * K + kt, &sA[b2][4096 + ldsW]);
        gload_lds16(pB + kt, &sB[b2][ldsW]);
      }
      const int cb = tt % 3;
      const char* bA = (const char*)&sA[cb][0];
      const char* bB = (const char*)&sB[cb][0];
      bf16x8 af[4], bff[4];
#pragma unroll
      for (int mt = 0; mt < 4; ++mt)
        af[mt] = *(const bf16x8*)(bA + (wm + mt * 16 + lr) * 64 + ((g * 16) ^ swz));
#pragma unroll
      for (int nt2 = 0; nt2 < 4; ++nt2)
        bff[nt2] = *(const bf16x8*)(bB + (wn + nt2 * 16 + lr) * 64 + ((g * 16) ^ swz));
#pragma unroll
      for (int mt = 0; mt < 4; ++mt)
#pragma unroll
        for (int nt2 = 0; nt2 < 4; ++nt2)
          acc[mt][nt2] = mfma16(af[mt], bff[nt2], acc[mt][nt2]);
      asm volatile("" ::: "memory");
    }

    const int col = lr;
#pragma unroll
    for (int mt = 0; mt < 4; ++mt) {
#pragma unroll
      for (int r = 0; r < 4; ++r) {
        const int m = m0 + wm + mt * 16 + g * 4 + r;
        size_t obase = 0;
        if constexpr (EPI == E_SCATTER) {  // window-reverse + roll(+3,+3)
          int wq = m / 49, nn = m - wq * 49;
          int bb = wq >> 8, wi = wq & 255;
          int hh = (wi >> 4) * 7 + nn / 7 + 3;        if (hh >= 112) hh -= 112;
          int cc = (wi & 15) * 7 + (nn - (nn / 7) * 7) + 3; if (cc >= 112) cc -= 112;
          obase = ((size_t)bb * 12544 + hh * 112 + cc) * 384;
        }
#pragma unroll
        for (int nt2 = 0; nt2 < 4; ++nt2) {
          const int j = n0 + wn + nt2 * 16 + col;
          float v = acc[mt][nt2][r] + bias[j];
          if constexpr (EPI == E_BF16) {
            outb[(size_t)m * N + j] = f2bf(v);
          } else if constexpr (EPI == E_BF16_SCALE) {
            outb[(size_t)m * N + j] = f2bf(v * QSCALE);
          } else if constexpr (EPI == E_GELU) {
            // tanh-form GELU; |dev| < 4e-4
            float z = v * (1.5957691216057308f + 0.0713548162726009f * v * v);
            float gg = v / (1.f + __expf(-z));
            outb[(size_t)m * N + j] = f2bf(gg);
          } else if constexpr (EPI == E_SCATTER) {
            outf1[obase + j] = res1[obase + j] + v;
            outf2[obase + j] = res2[obase + j] + v;
          } else {  // E_RESOUT: fp32 final output = mlp + residual (in-place)
            outf1[(size_t)m * N + j] = v + res1[(size_t)m * N + j];
          }
        }
      }
    }
  }
}

// One block per (window, head). S = (q2*scale) @ k1^T (+rpb+mask), softmax, O = P @ v1.
__global__ __launch_bounds__(256) void attn_kern(
    const unsigned short* __restrict__ q2,   // TOK x 384 (already *SCALE)
    const unsigned short* __restrict__ kv1,  // TOK x 768 (k | v)
    const int* __restrict__ rpi,             // 49 x 49
    const float* __restrict__ mask,          // 256 x 49 x 49
    const float* __restrict__ rpb,           // 169 x 12
    unsigned short* __restrict__ o) {        // TOK x 384
  const int w = blockIdx.x, h = blockIdx.y;
  __shared__ __align__(16) unsigned short sQ[64 * 32];
  __shared__ __align__(16) unsigned short sK[64 * 32];
  __shared__ __align__(16) unsigned short sVT[32 * 64];  // V^T: [n][k]
  __shared__ __align__(16) unsigned short sP[64 * 64];
  const int t = threadIdx.x, wv = t >> 6, l = t & 63;
  const int r = t >> 2, c = (t & 3) * 8;
  const u16x8 z8 = {0, 0, 0, 0, 0, 0, 0, 0};
  if (r < 49) {
    *(u16x8*)&sQ[r * 32 + c] = *(const u16x8*)&q2[((size_t)w * 49 + r) * 384 + h * 32 + c];
    *(u16x8*)&sK[r * 32 + c] = *(const u16x8*)&kv1[((size_t)w * 49 + r) * 768 + h * 32 + c];
    u16x8 vv = *(const u16x8*)&kv1[((size_t)w * 49 + r) * 768 + 384 + h * 32 + c];
#pragma unroll
    for (int e = 0; e < 8; ++e) sVT[(c + e) * 64 + r] = vv[e];
  } else {
    *(u16x8*)&sQ[r * 32 + c] = z8;
    *(u16x8*)&sK[r * 32 + c] = z8;
#pragma unroll
    for (int e = 0; e < 8; ++e) sVT[(c + e) * 64 + r] = 0;
  }
  __syncthreads();

  const int g = l >> 4, col = l & 15;
  const f32x4 fzero = {0.f, 0.f, 0.f, 0.f};
  bf16x8 aq = *(const bf16x8*)&sQ[(wv * 16 + col) * 32 + g * 8];
  f32x4 s[4];
#pragma unroll
  for (int nt = 0; nt < 4; ++nt) {
    bf16x8 bk = *(const bf16x8*)&sK[(nt * 16 + col) * 32 + g * 8];
    s[nt] = mfma16(aq, bk, fzero);
  }

  const int wi = w & 255;
  float p[4][4];
#pragma unroll
  for (int rr = 0; rr < 4; ++rr) {
    const int i = wv * 16 + g * 4 + rr;
    float mx = -1e30f;
#pragma unroll
    for (int nt = 0; nt < 4; ++nt) {
      const int j = nt * 16 + col;
      float val = -1e9f;
      if (i < 49 && j < 49)
        val = s[nt][rr] + rpb[rpi[i * 49 + j] * 12 + h] + mask[((size_t)wi * 49 + i) * 49 + j];
      p[nt][rr] = val;
      mx = fmaxf(mx, val);
    }
#pragma unroll
    for (int d = 1; d < 16; d <<= 1) mx = fmaxf(mx, __shfl_xor(mx, d));
    float sm = 0.f;
#pragma unroll
    for (int nt = 0; nt < 4; ++nt) {
      const int j = nt * 16 + col;
      float e = (j < 49) ? __expf(p[nt][rr] - mx) : 0.f;
      p[nt][rr] = e; sm += e;
    }
#pragma unroll
    for (int d = 1; d < 16; d <<= 1) sm += __shfl_xor(sm, d);
    const float inv = 1.f / sm;
#pragma unroll
    for (int nt = 0; nt < 4; ++nt) p[nt][rr] *= inv;
  }
#pragma unroll
  for (int rr = 0; rr < 4; ++rr) {
    const int i = wv * 16 + g * 4 + rr;
#pragma unroll
    for (int nt = 0; nt < 4; ++nt) sP[i * 64 + nt * 16 + col] = f2bf(p[nt][rr]);
  }
  __syncthreads();

  f32x4 oa[2] = {fzero, fzero};
#pragma unroll
  for (int ks = 0; ks < 2; ++ks) {
    bf16x8 ap = *(const bf16x8*)&sP[(wv * 16 + col) * 64 + ks * 32 + g * 8];
#pragma unroll
    for (int n2 = 0; n2 < 2; ++n2) {
      bf16x8 bv = *(const bf16x8*)&sVT[(n2 * 16 + col) * 64 + ks * 32 + g * 8];
      oa[n2] = mfma16(ap, bv, oa[n2]);
    }
  }
#pragma unroll
  for (int rr = 0; rr < 4; ++rr) {
    const int i = wv * 16 + g * 4 + rr;
    if (i < 49) {
#pragma unroll
      for (int n2 = 0; n2 < 2; ++n2)
        o[((size_t)w * 49 + i) * 384 + h * 32 + n2 * 16 + col] = f2bf(oa[n2][rr]);
    }
  }
}

extern "C" void kernel_launch(void* const* d_in, const int* in_sizes, int n_in,
                              void* d_out, int out_size, void* d_ws, size_t ws_size,
                              hipStream_t stream) {
  (void)in_sizes; (void)n_in; (void)out_size; (void)ws_size;
  const float* s1   = (const float*)d_in[0];
  const float* s2   = (const float*)d_in[1];
  const float* mask = (const float*)d_in[2];
  const int*   rpi  = (const int*)d_in[3];
  const float* n1w1 = (const float*)d_in[4],  *n1b1 = (const float*)d_in[5];
  const float* n1w2 = (const float*)d_in[6],  *n1b2 = (const float*)d_in[7];
  const float* qw1  = (const float*)d_in[8],  *qb1  = (const float*)d_in[9];
  const float* qw2  = (const float*)d_in[10], *qb2  = (const float*)d_in[11];
  const float* rpb1 = (const float*)d_in[12];
  // d_in[13] = rpb2 (dead)
  const float* pw1  = (const float*)d_in[14], *pb1  = (const float*)d_in[15];
  // d_in[16..17] = pw2/pb2 (dead)
  const float* n2w1 = (const float*)d_in[18], *n2b1 = (const float*)d_in[19];
  const float* n2w2 = (const float*)d_in[20], *n2b2 = (const float*)d_in[21];
  const float* m1fc1w = (const float*)d_in[22], *m1fc1b = (const float*)d_in[23];
  const float* m1fc2w = (const float*)d_in[24], *m1fc2b = (const float*)d_in[25];
  const float* m2fc1w = (const float*)d_in[26], *m2fc1b = (const float*)d_in[27];
  const float* m2fc2w = (const float*)d_in[28], *m2fc2b = (const float*)d_in[29];

  char* ws = (char*)d_ws;
  const size_t S1 = (size_t)TOK * DIMC * 2;  // 38,535,168 B
  unsigned short* x1w  = (unsigned short*)(ws);        // later: obuf, xm
  unsigned short* x2w  = (unsigned short*)(ws + S1);   // later: hbuf [S1,5S1)
  unsigned short* kv1  = (unsigned short*)(ws + 2 * S1);
  unsigned short* q2b  = (unsigned short*)(ws + 4 * S1);
  unsigned short* obuf = x1w;
  unsigned short* hbuf = x2w;   // TOK x 1536 bf16 = 4*S1, overlays x2w/kv1/q2b (dead by then)
  unsigned short* xm   = x1w;
  char* wp = ws + 5 * S1;  // bf16 weights, 5,898,240 B (total ws ~199 MB)
  unsigned short* wq1b = (unsigned short*)(wp);
  unsigned short* wq2b = (unsigned short*)(wp + 589824);
  unsigned short* wp1b = (unsigned short*)(wp + 884736);
  unsigned short* wf11 = (unsigned short*)(wp + 1179648);
  unsigned short* wf12 = (unsigned short*)(wp + 2359296);
  unsigned short* wf21 = (unsigned short*)(wp + 3538944);
  unsigned short* wf22 = (unsigned short*)(wp + 4718592);

  // Residual streams b1, b2 live directly in d_out (fp32, exactly TOK*384 each);
  // final MLP GEMM adds in-place (1:1 thread->element, no cross-thread hazard).
  float* outf = (float*)d_out;
  float* b1 = outf;
  float* b2 = outf + (size_t)19267584;

  // weights fp32 -> bf16 (qw1: skip q rows, keep k|v rows 384..1151)
  w2bf_kern<<<(294912 + 255) / 256, 256, 0, stream>>>(qw1 + 384 * 384, wq1b, 294912);
  w2bf_kern<<<(147456 + 255) / 256, 256, 0, stream>>>(qw2, wq2b, 147456);
  w2bf_kern<<<(147456 + 255) / 256, 256, 0, stream>>>(pw1, wp1b, 147456);
  w2bf_kern<<<(589824 + 255) / 256, 256, 0, stream>>>(m1fc1w, wf11, 589824);
  w2bf_kern<<<(589824 + 255) / 256, 256, 0, stream>>>(m1fc2w, wf12, 589824);
  w2bf_kern<<<(589824 + 255) / 256, 256, 0, stream>>>(m2fc1w, wf21, 589824);
  w2bf_kern<<<(589824 + 255) / 256, 256, 0, stream>>>(m2fc2w, wf22, 589824);

  // LN1 + roll + window partition
  ln_kern<true><<<TOK / 4, 256, 0, stream>>>(s1, n1w1, n1b1, x1w);
  ln_kern<true><<<TOK / 4, 256, 0, stream>>>(s2, n1w2, n1b2, x2w);

  // k1|v1 and q2 (q2 pre-scaled). persistent 512-block grids.
  gemm_bt<E_BF16><<<512, 512, 0, stream>>>(x1w, wq1b, qb1 + 384, 384, 768, 6, 1176,
                                           kv1, nullptr, nullptr, nullptr, nullptr);
  gemm_bt<E_BF16_SCALE><<<512, 512, 0, stream>>>(x2w, wq2b, qb2, 384, 384, 3, 588,
                                                 q2b, nullptr, nullptr, nullptr, nullptr);
  // attention
  attn_kern<<<dim3(1024, 12), 256, 0, stream>>>(q2b, kv1, rpi, mask, rpb1, obuf);

  // projection + window-reverse scatter + both residuals -> b1, b2 (fp32, in d_out)
  gemm_bt<E_SCATTER><<<512, 512, 0, stream>>>(obuf, wp1b, pb1, 384, 384, 3, 588,
                                              nullptr, b1, b2, s1, s2);
  // branch 1 MLP
  ln_kern<false><<<TOK / 4, 256, 0, stream>>>(b1, n2w1, n2b1, xm);
  gemm_bt<E_GELU><<<512, 512, 0, stream>>>(xm, wf11, m1fc1b, 384, 1536, 12, 2352,
                                           hbuf, nullptr, nullptr, nullptr, nullptr);
  gemm_bt<E_RESOUT><<<512, 512, 0, stream>>>(hbuf, wf12, m1fc2b, 1536, 384, 3, 588,
                                             nullptr, b1, nullptr, b1, nullptr);
  // branch 2 MLP
  ln_kern<false><<<TOK / 4, 256, 0, stream>>>(b2, n2w2, n2b2, xm);
  gemm_bt<E_GELU><<<512, 512, 0, stream>>>(xm, wf21, m2fc1b, 384, 1536, 12, 2352,
                                           hbuf, nullptr, nullptr, nullptr, nullptr);
  gemm_bt<E_RESOUT><<<512, 512, 0, stream>>>(hbuf, wf22, m2fc2b, 1536, 384, 3, 588,
                                             nullptr, b2, nullptr, b2, nullptr);
}

// Round 6
// 838.884 us; speedup vs baseline: 1.2263x; 1.2263x over previous
//
#include <hip/hip_runtime.h>
#include <math.h>

#define DEV __device__ __forceinline__

typedef __attribute__((ext_vector_type(8))) unsigned short u16x8;
typedef __attribute__((ext_vector_type(8))) __bf16 bf16x8;
typedef __attribute__((ext_vector_type(4))) float f32x4;

static constexpr int TOK = 50176;   // 1024 windows * 49 tokens = B*H*W
static constexpr int DIMC = 384;
static constexpr float QSCALE = 0.17677669529663687f;  // 32^-0.5

DEV unsigned short f2bf(float f) {   // round-to-nearest-even fp32 -> bf16 bits
  union { float f; unsigned u; } v; v.f = f;
  unsigned r = v.u + 0x7fffu + ((v.u >> 16) & 1u);
  return (unsigned short)(r >> 16);
}

DEV float bf2f(unsigned short b) {
  union { unsigned u; float f; } v; v.u = ((unsigned)b) << 16; return v.f;
}

DEV f32x4 mfma16(bf16x8 a, bf16x8 b, f32x4 c) {
  return __builtin_amdgcn_mfma_f32_16x16x32_bf16(a, b, c, 0, 0, 0);
}

DEV void gload_lds16(const void* g, void* lds) {
  __builtin_amdgcn_global_load_lds(
      (const __attribute__((address_space(1))) void*)g,
      (__attribute__((address_space(3))) void*)lds, 16, 0, 0);
}

// All 7 weight fp32->bf16 conversions in one launch (segment if-chain on blockIdx).
__global__ __launch_bounds__(256) void w2bf7_kern(
    const float* __restrict__ s0, const float* __restrict__ s1,
    const float* __restrict__ s2, const float* __restrict__ s3,
    const float* __restrict__ s4, const float* __restrict__ s5,
    const float* __restrict__ s6,
    unsigned short* __restrict__ d0, unsigned short* __restrict__ d1,
    unsigned short* __restrict__ d2, unsigned short* __restrict__ d3,
    unsigned short* __restrict__ d4, unsigned short* __restrict__ d5,
    unsigned short* __restrict__ d6) {
  const int b = blockIdx.x;
  const float* src; unsigned short* dst; int off;
  if      (b < 1152) { src = s0; dst = d0; off = b; }
  else if (b < 1728) { src = s1; dst = d1; off = b - 1152; }
  else if (b < 2304) { src = s2; dst = d2; off = b - 1728; }
  else if (b < 4608) { src = s3; dst = d3; off = b - 2304; }
  else if (b < 6912) { src = s4; dst = d4; off = b - 4608; }
  else if (b < 9216) { src = s5; dst = d5; off = b - 6912; }
  else               { src = s6; dst = d6; off = b - 9216; }
  const int i = off * 256 + threadIdx.x;
  dst[i] = f2bf(src[i]);  // all segment sizes are multiples of 256
}

// Fused attention bias: bias[wi][h][i(64)][j(64)] = rpb[rpi[i,j],h] + mask[wi,i,j],
// -1e9 padding outside 49x49 (j>=49 acts as softmax -inf; i>=49 rows unused).
__global__ __launch_bounds__(256) void bias_kern(const int* __restrict__ rpi,
                                                 const float* __restrict__ mask,
                                                 const float* __restrict__ rpb,
                                                 unsigned short* __restrict__ out) {
  const int wh = blockIdx.x;              // wi*12 + h, 0..3071
  const int wi = wh / 12, h = wh - wi * 12;
  const int t = threadIdx.x;
#pragma unroll
  for (int k = 0; k < 16; ++k) {
    const int idx = k * 256 + t;          // 0..4095
    const int i = idx >> 6, j = idx & 63;
    float v = -1e9f;
    if (i < 49 && j < 49)
      v = rpb[rpi[i * 49 + j] * 12 + h] + mask[(size_t)wi * 2401 + i * 49 + j];
    out[(size_t)wh * 4096 + idx] = f2bf(v);
  }
}

// LayerNorm; WINDOW=true also applies roll(-3,-3)+window partition (gather form).
template<bool WINDOW>
__global__ __launch_bounds__(256) void ln_kern(const float* __restrict__ in,
                                               const float* __restrict__ gw,
                                               const float* __restrict__ gb,
                                               unsigned short* __restrict__ out) {
  const int row = blockIdx.x * 4 + (threadIdx.x >> 6);  // output row
  const int l = threadIdx.x & 63;
  int src = row;
  if (WINDOW) {
    const int wq = row / 49, nn = row - wq * 49;
    const int bb = wq >> 8, wi = wq & 255;
    int hh = (wi >> 4) * 7 + nn / 7 + 3;        if (hh >= 112) hh -= 112;
    int cc = (wi & 15) * 7 + (nn - (nn / 7) * 7) + 3; if (cc >= 112) cc -= 112;
    src = bb * 12544 + hh * 112 + cc;
  }
  const float* x = in + (size_t)src * DIMC;
  float v[6]; float s = 0.f, s2 = 0.f;
#pragma unroll
  for (int j = 0; j < 6; ++j) { float t = x[l + 64 * j]; v[j] = t; s += t; s2 += t * t; }
#pragma unroll
  for (int d = 1; d < 64; d <<= 1) { s += __shfl_xor(s, d); s2 += __shfl_xor(s2, d); }
  const float mean = s * (1.f / 384.f);
  const float var = s2 * (1.f / 384.f) - mean * mean;
  const float rs = rsqrtf(var + 1e-5f);
#pragma unroll
  for (int j = 0; j < 6; ++j) {
    int c = l + 64 * j;
    out[(size_t)row * DIMC + c] = f2bf((v[j] - mean) * rs * gw[c] + gb[c]);
  }
}

enum { E_BF16 = 0, E_BF16_SCALE = 1, E_SCATTER = 2, E_GELU = 3, E_RESOUT = 4 };

// C = A(MxK) @ W(NxK)^T + bias. 128x128 tile, BK=32, 4 waves.  (round-4 config:
// best measured; R5's 256x128/512thr persistent variant dropped to 1 block/CU
// and regressed — keep >=3 small blocks/CU for this family.)
// 3-buffer LDS rotation, ONE barrier per K-step, counted vmcnt(4) (2-tile
// prefetch depth). XOR-swizzle both-sides (rule #21). 1-D grid, col-fast
// decode + bijective XCD swizzle (m204) for weight-panel L2 reuse.
template<int EPI>
__global__ __launch_bounds__(256) void gemm_bt(
    const unsigned short* __restrict__ A, const unsigned short* __restrict__ W,
    const float* __restrict__ bias, int K, int N, int nbx,
    unsigned short* __restrict__ outb,
    float* __restrict__ outf1, float* __restrict__ outf2,
    const float* __restrict__ res1, const float* __restrict__ res2) {
  __shared__ __align__(16) unsigned short sA[3][128 * 32];
  __shared__ __align__(16) unsigned short sB[3][128 * 32];
  const int t = threadIdx.x;
  const int wv = t >> 6, l = t & 63;
  const int wm = (wv >> 1) * 64, wn = (wv & 1) * 64;

  // bijective XCD swizzle: each XCD gets a contiguous chunk of the col-fast order
  const int total = gridDim.x;
  const int q = total >> 3, rr8 = total & 7;
  const int xcd = blockIdx.x & 7, lid = blockIdx.x >> 3;
  const int wgid = (xcd < rr8 ? xcd * (q + 1) : rr8 * (q + 1) + (xcd - rr8) * q) + lid;
  const int n0 = (wgid % nbx) * 128, m0 = (wgid / nbx) * 128;

  // staging: thread t -> row (t>>2) in 64-row round, slot (t&3); source col pre-swizzled
  const int srow = t >> 2;                                  // 0..63
  const int scol = ((t & 3) ^ ((t >> 3) & 3)) * 8;          // elements

  f32x4 acc[4][4];
  const f32x4 fzero = {0.f, 0.f, 0.f, 0.f};
#pragma unroll
  for (int i = 0; i < 4; ++i)
#pragma unroll
    for (int j = 0; j < 4; ++j) acc[i][j] = fzero;

  const unsigned short* gA = A + (size_t)(m0 + srow) * K + scol;
  const unsigned short* gB = W + (size_t)(n0 + srow) * K + scol;
  const int ldsW = wv * 512;  // per-wave 1KB chunk (elements) within 4KB round

  const int g = l >> 4, lr = l & 15;
  const int swz = ((lr >> 1) & 3) << 4;  // read-side XOR (bytes)

  const int ntt = K >> 5;
  // prologue: stage tiles 0 and 1
#pragma unroll
  for (int p = 0; p < 2; ++p) {
#pragma unroll
    for (int it = 0; it < 2; ++it) {
      gload_lds16(gA + (size_t)(it * 64) * K + p * 32, &sA[p][it * 2048 + ldsW]);
      gload_lds16(gB + (size_t)(it * 64) * K + p * 32, &sB[p][it * 2048 + ldsW]);
    }
  }
  for (int tt = 0; tt < ntt; ++tt) {
    if (tt + 1 < ntt) {
      asm volatile("s_waitcnt vmcnt(4)" ::: "memory");  // drain tile tt, keep tt+1 in flight
    } else {
      asm volatile("s_waitcnt vmcnt(0)" ::: "memory");
    }
    __builtin_amdgcn_s_barrier();
    asm volatile("" ::: "memory");
    if (tt + 2 < ntt) {  // stage tile tt+2 into buf (tt+2)%3 (last read at iter tt-1)
      const int kt = (tt + 2) << 5;
      const int b2 = (tt + 2) % 3;
#pragma unroll
      for (int it = 0; it < 2; ++it) {
        gload_lds16(gA + (size_t)(it * 64) * K + kt, &sA[b2][it * 2048 + ldsW]);
        gload_lds16(gB + (size_t)(it * 64) * K + kt, &sB[b2][it * 2048 + ldsW]);
      }
    }
    const int cb = tt % 3;
    const char* bA = (const char*)&sA[cb][0];
    const char* bB = (const char*)&sB[cb][0];
    bf16x8 af[4], bff[4];
#pragma unroll
    for (int mt = 0; mt < 4; ++mt)
      af[mt] = *(const bf16x8*)(bA + (wm + mt * 16 + lr) * 64 + ((g * 16) ^ swz));
#pragma unroll
    for (int nt2 = 0; nt2 < 4; ++nt2)
      bff[nt2] = *(const bf16x8*)(bB + (wn + nt2 * 16 + lr) * 64 + ((g * 16) ^ swz));
    __builtin_amdgcn_s_setprio(1);
#pragma unroll
    for (int mt = 0; mt < 4; ++mt)
#pragma unroll
      for (int nt2 = 0; nt2 < 4; ++nt2)
        acc[mt][nt2] = mfma16(af[mt], bff[nt2], acc[mt][nt2]);
    __builtin_amdgcn_s_setprio(0);
    asm volatile("" ::: "memory");
  }

  const int col = lr;
#pragma unroll
  for (int mt = 0; mt < 4; ++mt) {
#pragma unroll
    for (int r = 0; r < 4; ++r) {
      const int m = m0 + wm + mt * 16 + g * 4 + r;
      size_t obase = 0;
      if constexpr (EPI == E_SCATTER) {  // window-reverse + roll(+3,+3): same map as gather
        int wq = m / 49, nn = m - wq * 49;
        int bb = wq >> 8, wi = wq & 255;
        int hh = (wi >> 4) * 7 + nn / 7 + 3;        if (hh >= 112) hh -= 112;
        int cc = (wi & 15) * 7 + (nn - (nn / 7) * 7) + 3; if (cc >= 112) cc -= 112;
        obase = ((size_t)bb * 12544 + hh * 112 + cc) * 384;
      }
#pragma unroll
      for (int nt2 = 0; nt2 < 4; ++nt2) {
        const int j = n0 + wn + nt2 * 16 + col;
        float v = acc[mt][nt2][r] + bias[j];
        if constexpr (EPI == E_BF16) {
          outb[(size_t)m * N + j] = f2bf(v);
        } else if constexpr (EPI == E_BF16_SCALE) {
          outb[(size_t)m * N + j] = f2bf(v * QSCALE);
        } else if constexpr (EPI == E_GELU) {
          // tanh-form GELU; |dev| < 4e-4
          float z = v * (1.5957691216057308f + 0.0713548162726009f * v * v);
          float gg = v / (1.f + __expf(-z));
          outb[(size_t)m * N + j] = f2bf(gg);
        } else if constexpr (EPI == E_SCATTER) {
          outf1[obase + j] = res1[obase + j] + v;
          outf2[obase + j] = res2[obase + j] + v;
        } else {  // E_RESOUT: fp32 final output = mlp + residual (in-place over residual)
          outf1[(size_t)m * N + j] = v + res1[(size_t)m * N + j];
        }
      }
    }
  }
}

// One block per (window, head). S = (q2*scale) @ k1^T + bias(LDS), softmax, O = P @ v1.
// All rpi/rpb/mask gathers replaced by the precomputed bias table (bf16, LDS-staged).
__global__ __launch_bounds__(256) void attn_kern(
    const unsigned short* __restrict__ q2,    // TOK x 384 (already *SCALE)
    const unsigned short* __restrict__ kv1,   // TOK x 768 (k | v)
    const unsigned short* __restrict__ biasb, // 256 x 12 x 64 x 64 bf16
    unsigned short* __restrict__ o) {         // TOK x 384
  const int w = blockIdx.x, h = blockIdx.y;
  __shared__ __align__(16) unsigned short sQ[64 * 32];
  __shared__ __align__(16) unsigned short sK[64 * 32];
  __shared__ __align__(16) unsigned short sVT[32 * 64];   // V^T: [n][k]
  __shared__ __align__(16) unsigned short sP[64 * 64];
  __shared__ __align__(16) unsigned short sBias[64 * 64];
  const int t = threadIdx.x, wv = t >> 6, l = t & 63;
  const int r = t >> 2, c = (t & 3) * 8;
  const u16x8 z8 = {0, 0, 0, 0, 0, 0, 0, 0};
  const unsigned short* bsrc = biasb + (((size_t)(w & 255) * 12 + h) << 12);
  *(u16x8*)&sBias[t * 8] = *(const u16x8*)&bsrc[t * 8];
  *(u16x8*)&sBias[2048 + t * 8] = *(const u16x8*)&bsrc[2048 + t * 8];
  if (r < 49) {
    *(u16x8*)&sQ[r * 32 + c] = *(const u16x8*)&q2[((size_t)w * 49 + r) * 384 + h * 32 + c];
    *(u16x8*)&sK[r * 32 + c] = *(const u16x8*)&kv1[((size_t)w * 49 + r) * 768 + h * 32 + c];
    u16x8 vv = *(const u16x8*)&kv1[((size_t)w * 49 + r) * 768 + 384 + h * 32 + c];
#pragma unroll
    for (int e = 0; e < 8; ++e) sVT[(c + e) * 64 + r] = vv[e];
  } else {
    *(u16x8*)&sQ[r * 32 + c] = z8;
    *(u16x8*)&sK[r * 32 + c] = z8;
#pragma unroll
    for (int e = 0; e < 8; ++e) sVT[(c + e) * 64 + r] = 0;
  }
  __syncthreads();

  const int g = l >> 4, col = l & 15;
  const f32x4 fzero = {0.f, 0.f, 0.f, 0.f};
  bf16x8 aq = *(const bf16x8*)&sQ[(wv * 16 + col) * 32 + g * 8];
  f32x4 s[4];
#pragma unroll
  for (int nt = 0; nt < 4; ++nt) {
    bf16x8 bk = *(const bf16x8*)&sK[(nt * 16 + col) * 32 + g * 8];
    s[nt] = mfma16(aq, bk, fzero);
  }

  float p[4][4];
#pragma unroll
  for (int rr = 0; rr < 4; ++rr) {
    const int i = wv * 16 + g * 4 + rr;
    float mx = -1e30f;
#pragma unroll
    for (int nt = 0; nt < 4; ++nt) {
      const int j = nt * 16 + col;
      float val = s[nt][rr] + bf2f(sBias[i * 64 + j]);
      p[nt][rr] = val;
      mx = fmaxf(mx, val);
    }
#pragma unroll
    for (int d = 1; d < 16; d <<= 1) mx = fmaxf(mx, __shfl_xor(mx, d));
    float sm = 0.f;
#pragma unroll
    for (int nt = 0; nt < 4; ++nt) {
      float e = __expf(p[nt][rr] - mx);
      p[nt][rr] = e; sm += e;
    }
#pragma unroll
    for (int d = 1; d < 16; d <<= 1) sm += __shfl_xor(sm, d);
    const float inv = 1.f / sm;
#pragma unroll
    for (int nt = 0; nt < 4; ++nt) p[nt][rr] *= inv;
  }
#pragma unroll
  for (int rr = 0; rr < 4; ++rr) {
    const int i = wv * 16 + g * 4 + rr;
#pragma unroll
    for (int nt = 0; nt < 4; ++nt) sP[i * 64 + nt * 16 + col] = f2bf(p[nt][rr]);
  }
  __syncthreads();

  f32x4 oa[2] = {fzero, fzero};
#pragma unroll
  for (int ks = 0; ks < 2; ++ks) {
    bf16x8 ap = *(const bf16x8*)&sP[(wv * 16 + col) * 64 + ks * 32 + g * 8];
#pragma unroll
    for (int n2 = 0; n2 < 2; ++n2) {
      bf16x8 bv = *(const bf16x8*)&sVT[(n2 * 16 + col) * 64 + ks * 32 + g * 8];
      oa[n2] = mfma16(ap, bv, oa[n2]);
    }
  }
#pragma unroll
  for (int rr = 0; rr < 4; ++rr) {
    const int i = wv * 16 + g * 4 + rr;
    if (i < 49) {
#pragma unroll
      for (int n2 = 0; n2 < 2; ++n2)
        o[((size_t)w * 49 + i) * 384 + h * 32 + n2 * 16 + col] = f2bf(oa[n2][rr]);
    }
  }
}

extern "C" void kernel_launch(void* const* d_in, const int* in_sizes, int n_in,
                              void* d_out, int out_size, void* d_ws, size_t ws_size,
                              hipStream_t stream) {
  (void)in_sizes; (void)n_in; (void)out_size; (void)ws_size;
  const float* s1   = (const float*)d_in[0];
  const float* s2   = (const float*)d_in[1];
  const float* mask = (const float*)d_in[2];
  const int*   rpi  = (const int*)d_in[3];
  const float* n1w1 = (const float*)d_in[4],  *n1b1 = (const float*)d_in[5];
  const float* n1w2 = (const float*)d_in[6],  *n1b2 = (const float*)d_in[7];
  const float* qw1  = (const float*)d_in[8],  *qb1  = (const float*)d_in[9];
  const float* qw2  = (const float*)d_in[10], *qb2  = (const float*)d_in[11];
  const float* rpb1 = (const float*)d_in[12];
  // d_in[13] = rpb2 (dead)
  const float* pw1  = (const float*)d_in[14], *pb1  = (const float*)d_in[15];
  // d_in[16..17] = pw2/pb2 (dead)
  const float* n2w1 = (const float*)d_in[18], *n2b1 = (const float*)d_in[19];
  const float* n2w2 = (const float*)d_in[20], *n2b2 = (const float*)d_in[21];
  const float* m1fc1w = (const float*)d_in[22], *m1fc1b = (const float*)d_in[23];
  const float* m1fc2w = (const float*)d_in[24], *m1fc2b = (const float*)d_in[25];
  const float* m2fc1w = (const float*)d_in[26], *m2fc1b = (const float*)d_in[27];
  const float* m2fc2w = (const float*)d_in[28], *m2fc2b = (const float*)d_in[29];

  char* ws = (char*)d_ws;
  const size_t S1 = (size_t)TOK * DIMC * 2;  // 38,535,168 B
  unsigned short* x1w  = (unsigned short*)(ws);        // later: obuf, xm
  unsigned short* x2w  = (unsigned short*)(ws + S1);   // later: biasb, then hbuf
  unsigned short* kv1  = (unsigned short*)(ws + 2 * S1);
  unsigned short* q2b  = (unsigned short*)(ws + 4 * S1);
  unsigned short* obuf = x1w;
  unsigned short* biasb = x2w;  // 25.2 MB <= S1; alive only between q2-GEMM and MLP
  unsigned short* hbuf = x2w;   // TOK x 1536 bf16 = 4*S1, overlays x2w/kv1/q2b (dead by then)
  unsigned short* xm   = x1w;
  char* wp = ws + 5 * S1;  // bf16 weights, 5,898,240 B (total ws ~199 MB)
  unsigned short* wq1b = (unsigned short*)(wp);
  unsigned short* wq2b = (unsigned short*)(wp + 589824);
  unsigned short* wp1b = (unsigned short*)(wp + 884736);
  unsigned short* wf11 = (unsigned short*)(wp + 1179648);
  unsigned short* wf12 = (unsigned short*)(wp + 2359296);
  unsigned short* wf21 = (unsigned short*)(wp + 3538944);
  unsigned short* wf22 = (unsigned short*)(wp + 4718592);

  // Residual streams b1, b2 live directly in d_out (fp32, exactly TOK*384 each);
  // final MLP GEMM adds in-place (1:1 thread->element, no cross-thread hazard).
  float* outf = (float*)d_out;
  float* b1 = outf;
  float* b2 = outf + (size_t)19267584;

  // all weight fp32->bf16 conversions in one launch (qw1: k|v rows 384..1151 only)
  w2bf7_kern<<<11520, 256, 0, stream>>>(qw1 + 384 * 384, qw2, pw1,
                                        m1fc1w, m1fc2w, m2fc1w, m2fc2w,
                                        wq1b, wq2b, wp1b, wf11, wf12, wf21, wf22);

  // LN1 + roll + window partition
  ln_kern<true><<<TOK / 4, 256, 0, stream>>>(s1, n1w1, n1b1, x1w);
  ln_kern<true><<<TOK / 4, 256, 0, stream>>>(s2, n1w2, n1b2, x2w);

  // k1|v1 and q2 (q2 pre-scaled)
  gemm_bt<E_BF16><<<6 * 392, 256, 0, stream>>>(x1w, wq1b, qb1 + 384, 384, 768, 6,
                                               kv1, nullptr, nullptr, nullptr, nullptr);
  gemm_bt<E_BF16_SCALE><<<3 * 392, 256, 0, stream>>>(x2w, wq2b, qb2, 384, 384, 3,
                                                     q2b, nullptr, nullptr, nullptr, nullptr);
  // fused attention bias table (into x2w slot, now dead) then attention
  bias_kern<<<3072, 256, 0, stream>>>(rpi, mask, rpb1, biasb);
  attn_kern<<<dim3(1024, 12), 256, 0, stream>>>(q2b, kv1, biasb, obuf);

  // projection + window-reverse scatter + both residuals -> b1, b2 (fp32, in d_out)
  gemm_bt<E_SCATTER><<<3 * 392, 256, 0, stream>>>(obuf, wp1b, pb1, 384, 384, 3,
                                                  nullptr, b1, b2, s1, s2);
  // branch 1 MLP
  ln_kern<false><<<TOK / 4, 256, 0, stream>>>(b1, n2w1, n2b1, xm);
  gemm_bt<E_GELU><<<12 * 392, 256, 0, stream>>>(xm, wf11, m1fc1b, 384, 1536, 12,
                                                hbuf, nullptr, nullptr, nullptr, nullptr);
  gemm_bt<E_RESOUT><<<3 * 392, 256, 0, stream>>>(hbuf, wf12, m1fc2b, 1536, 384, 3,
                                                 nullptr, b1, nullptr, b1, nullptr);
  // branch 2 MLP
  ln_kern<false><<<TOK / 4, 256, 0, stream>>>(b2, n2w2, n2b2, xm);
  gemm_bt<E_GELU><<<12 * 392, 256, 0, stream>>>(xm, wf21, m2fc1b, 384, 1536, 12,
                                                hbuf, nullptr, nullptr, nullptr, nullptr);
  gemm_bt<E_RESOUT><<<3 * 392, 256, 0, stream>>>(hbuf, wf22, m2fc2b, 1536, 384, 3,
                                                 nullptr, b2, nullptr, b2, nullptr);
}